// Round 16
// baseline (132.707 us; speedup 1.0000x reference)
//
#include <hip/hip_runtime.h>
#include <stdint.h>

typedef __attribute__((ext_vector_type(8)))  __bf16 bf16x8;
typedef __attribute__((ext_vector_type(4)))  float  f32x4;
typedef __attribute__((ext_vector_type(16))) float  f32x16;
typedef __attribute__((ext_vector_type(8)))  ushort u16x8;
typedef __attribute__((ext_vector_type(4)))  ushort u16x4;
typedef __attribute__((ext_vector_type(4)))  uint   u32x4;

#define LOG2E 1.44269504088896f

__device__ __forceinline__ ushort f2bf(float f) {
  uint32_t u = __float_as_uint(f);
  u += 0x7fffu + ((u >> 16) & 1u);   // RNE
  return (ushort)(u >> 16);
}
__device__ __forceinline__ float bf2f(ushort h) {
  return __uint_as_float(((uint32_t)h) << 16);
}
__device__ __forceinline__ void gload16(const void* g, void* l) {
  __builtin_amdgcn_global_load_lds((const __attribute__((address_space(1))) void*)g,
                                   (__attribute__((address_space(3))) void*)l, 16, 0, 0);
}
__device__ __forceinline__ f32x4 mfma16(bf16x8 a, bf16x8 b, f32x4 c) {
  return __builtin_amdgcn_mfma_f32_16x16x32_bf16(a, b, c, 0, 0, 0);
}
__device__ __forceinline__ f32x16 mfma32(bf16x8 a, bf16x8 b, f32x16 c) {
  return __builtin_amdgcn_mfma_f32_32x32x16_bf16(a, b, c, 0, 0, 0);
}
// LDS XOR swizzle for 128B rows (m214 G4): byte ^= (row&7)<<4
__device__ __forceinline__ int swz(int row, int byteoff) {
  return row * 128 + (byteoff ^ ((row & 7) << 4));
}
__device__ __forceinline__ uint cvtpk(float lo, float hi) {
  uint w;
  asm("v_cvt_pk_bf16_f32 %0, %1, %2" : "=v"(w) : "v"(lo), "v"(hi));
  return w;
}
__device__ __forceinline__ void plswap(uint& a, uint& b) {
  asm("v_permlane32_swap_b32 %0, %1" : "+v"(a), "+v"(b));
}
// NOTE (R7/R8): permlane cross-half merge idiom FAILED on HW twice (~6e-2).
// NOTE (R11): split-KV (2x blocks) = ZERO attn speedup (throughput-bound).
// NOTE (R13): gload_lds+dbuf attn staging = +13% REGRESSION vs reg-staging
// (the vmcnt(0) drain at the barrier serialized the global loads; the
// reg-staged path keeps the T14 issue-early/write-late split).
// NOTE (R14): no-max softmax = null; attn is issue-port saturated
// (MFMA 22% + VALU 27% + DS ~28%); small VALU cuts don't move it.
// NOTE (R16): dbuf + reg-staging (this round) isolates "1 barrier/tile vs 2"
// as the single variable.

// ---------------- batched fp32 -> bf16 (weights + activations), ONE launch ----
struct CvtArgs { const float* src[7]; ushort* dst[7]; };

__global__ __launch_bounds__(256) void cvt_all(CvtArgs a) {
  const int bid = blockIdx.x;
  int seg, base;
  if (bid < 2048) { seg = bid >> 9;              base = bid & 511; }
  else            { seg = 4 + ((bid - 2048) >> 11); base = (bid - 2048) & 2047; }
  const int i = base * 256 + threadIdx.x;   // n8 index
  const f32x4* s = (const f32x4*)a.src[seg];
  f32x4 x = s[2 * i], y = s[2 * i + 1];
  u16x8 o;
  o[0] = f2bf(x[0]); o[1] = f2bf(x[1]); o[2] = f2bf(x[2]); o[3] = f2bf(x[3]);
  o[4] = f2bf(y[0]); o[5] = f2bf(y[1]); o[6] = f2bf(y[2]); o[7] = f2bf(y[3]);
  ((u16x8*)a.dst[seg])[i] = o;
}

// ---------------- QKV projection GEMM: bf16, BK=64, XOR-swizzled tiles ----
// (R12-validated) LDS linear dest; slot permutation in per-lane SOURCE addr.
struct QKVArgs {
  const ushort* A0; const ushort* A1; const ushort* A2;
  const ushort* W0; const ushort* W1; const ushort* W2;
  const float* b0; const float* b1; const float* b2;
  ushort* Qo; ushort* Ko; ushort* Vo;
};

__global__ __launch_bounds__(256) void qkv_gemm(QKVArgs args) {
  __shared__ ushort Ash[128 * 64];   // 16 KB
  __shared__ ushort Bsh[128 * 64];   // 16 KB

  const int z = blockIdx.z;
  const ushort* Ab   = z == 0 ? args.A0 : (z == 1 ? args.A1 : args.A2);
  const ushort* Wb   = z == 0 ? args.W0 : (z == 1 ? args.W1 : args.W2);
  const float*  bias = z == 0 ? args.b0 : (z == 1 ? args.b1 : args.b2);

  const int tid = threadIdx.x;
  const int lane = tid & 63, wid = tid >> 6;
  const int l15 = lane & 15, g = lane >> 4;
  const int wr = wid >> 1, wc = wid & 1;
  const int tm = blockIdx.x * 128, tn = blockIdx.y * 128;

  const f32x4 fz = {0.f, 0.f, 0.f, 0.f};
  f32x4 acc[4][4];
#pragma unroll
  for (int m = 0; m < 4; ++m)
#pragma unroll
    for (int n = 0; n < 4; ++n) acc[m][n] = fz;

  const int srow8 = lane >> 3;                 // row within 8-row chunk
  const int ssl   = (lane & 7) ^ srow8;        // pre-swizzled source slot

  for (int kt = 0; kt < 1024; kt += 64) {
#pragma unroll
    for (int c = 0; c < 4; ++c) {
      const int chunk = wid * 4 + c;           // 16 chunks of 8 rows x 128B
      const int row = chunk * 8 + srow8;
      gload16(Wb + (size_t)(tn + row) * 1024 + kt + ssl * 8, &Bsh[chunk * 512]);
      gload16(Ab + (size_t)(tm + row) * 1024 + kt + ssl * 8, &Ash[chunk * 512]);
    }
    __syncthreads();

#pragma unroll
    for (int kk = 0; kk < 2; ++kk) {
      bf16x8 af[4], bfr[4];
#pragma unroll
      for (int m = 0; m < 4; ++m) {
        const int row = wr * 64 + m * 16 + l15;
        af[m] = *(const bf16x8*)&Ash[row * 64 + (((kk * 4 + g) ^ (row & 7)) * 8)];
      }
#pragma unroll
      for (int n = 0; n < 4; ++n) {
        const int row = wc * 64 + n * 16 + l15;
        bfr[n] = *(const bf16x8*)&Bsh[row * 64 + (((kk * 4 + g) ^ (row & 7)) * 8)];
      }
#pragma unroll
      for (int m = 0; m < 4; ++m)
#pragma unroll
        for (int n = 0; n < 4; ++n) acc[m][n] = mfma16(af[m], bfr[n], acc[m][n]);
    }
    __syncthreads();
  }

#pragma unroll
  for (int n = 0; n < 4; ++n) {
    const int col = tn + wc * 64 + n * 16 + l15;
    const float bv = bias[col];
    const int h = col >> 6, d = col & 63;
#pragma unroll
    for (int m = 0; m < 4; ++m) {
      const int row0 = tm + wr * 64 + m * 16 + g * 4;
      if (z == 2) {            // V^T : [B,H,Dh,S]
        const int b = row0 >> 11, s0 = row0 & 2047;
        u16x4 pk;
#pragma unroll
        for (int r = 0; r < 4; ++r) pk[r] = f2bf(acc[m][n][r] + bv);
        *(u16x4*)&args.Vo[((size_t)((b * 16 + h) * 64 + d)) * 2048 + s0] = pk;
      } else {                 // Q/K : [B,H,S,Dh]
        ushort* O = z ? args.Ko : args.Qo;
#pragma unroll
        for (int r = 0; r < 4; ++r) {
          const int row = row0 + r;
          const int b = row >> 11, s = row & 2047;
          O[((size_t)(b * 16 + h) * 2048 + s) * 64 + d] = f2bf(acc[m][n][r] + bv);
        }
      }
    }
  }
}

// ---------------- flash attention: reg-staged (R12) + LDS dbuf, 1 barrier/tile ----
__global__ __launch_bounds__(256) void attn_fwd(const ushort* __restrict__ Qb,
                                                const ushort* __restrict__ Kb,
                                                const ushort* __restrict__ VTb,
                                                ushort* __restrict__ ctxb) {
  __shared__ char Ksh[2][64 * 128];
  __shared__ char Vsh[2][64 * 128];
  __shared__ float Ssc[4][32];

  const int tid = threadIdx.x;
  const int lane = tid & 63, wid = tid >> 6;
  const int l31 = lane & 31, hi = lane >> 5;
  const int bh = blockIdx.y;
  const int q0 = blockIdx.x * 128 + wid * 32;

  const ushort* Qh = Qb + (size_t)bh * 2048 * 64;
  const ushort* Kh = Kb + (size_t)bh * 2048 * 64;
  const ushort* Vh = VTb + (size_t)bh * 64 * 2048;

  bf16x8 qf[4];
  {
    const ushort* qrow = Qh + (size_t)(q0 + l31) * 64;
#pragma unroll
    for (int dt = 0; dt < 4; ++dt) {
      u16x8 raw = *(const u16x8*)&qrow[dt * 16 + hi * 8];
      u16x8 sc;
#pragma unroll
      for (int j = 0; j < 8; ++j) sc[j] = f2bf(bf2f(raw[j]) * 0.125f);
      qf[dt] = __builtin_bit_cast(bf16x8, sc);
    }
  }

  f32x16 o0 = {}, o1 = {};
  float m = -1e30f, lsum = 0.f;

  const int si = tid >> 2, sc4i = tid & 3;
  const ushort* kg = &Kh[(size_t)si * 64 + sc4i * 16];
  const ushort* vg = &Vh[(size_t)si * 2048 + sc4i * 16];

  u16x8 kr0, kr1, vr0, vr1;
  // prologue: stage tile 0 into buf 0
  kr0 = *(const u16x8*)kg;  kr1 = *(const u16x8*)(kg + 8);
  vr0 = *(const u16x8*)vg;  vr1 = *(const u16x8*)(vg + 8);
  *(u16x8*)(Ksh[0] + swz(si, sc4i * 32))      = kr0;
  *(u16x8*)(Ksh[0] + swz(si, sc4i * 32 + 16)) = kr1;
  *(u16x8*)(Vsh[0] + swz(si, sc4i * 32))      = vr0;
  *(u16x8*)(Vsh[0] + swz(si, sc4i * 32 + 16)) = vr1;
  __syncthreads();

  for (int t = 0; t < 32; ++t) {
    const int cur = t & 1;
    if (t + 1 < 32) {          // T14: issue next tile's global loads early
      const int kt2 = (t + 1) * 64;
      kr0 = *(const u16x8*)(kg + (size_t)kt2 * 64);
      kr1 = *(const u16x8*)(kg + (size_t)kt2 * 64 + 8);
      vr0 = *(const u16x8*)(vg + kt2);
      vr1 = *(const u16x8*)(vg + kt2 + 8);
    }

    f32x16 P0 = {}, P1 = {};
    __builtin_amdgcn_s_setprio(1);
#pragma unroll
    for (int dt = 0; dt < 4; ++dt) {
      bf16x8 kf0 = *(const bf16x8*)(Ksh[cur] + swz(l31,      dt * 32 + hi * 16));
      bf16x8 kf1 = *(const bf16x8*)(Ksh[cur] + swz(32 + l31, dt * 32 + hi * 16));
      P0 = mfma32(kf0, qf[dt], P0);
      P1 = mfma32(kf1, qf[dt], P1);
    }
    __builtin_amdgcn_s_setprio(0);

    // local max via v_max3 chains (exact reassociation)
    float pm = fmaxf(P0[0], P1[0]);
#pragma unroll
    for (int r = 1; r + 1 < 16; r += 2) {
      pm = fmaxf(fmaxf(pm, P0[r]), P0[r + 1]);
      pm = fmaxf(fmaxf(pm, P1[r]), P1[r + 1]);
    }
    pm = fmaxf(fmaxf(pm, P0[15]), P1[15]);
    pm = fmaxf(pm, __shfl_xor(pm, 32));   // cross-half merge (validated path)

    if (!__all(pm <= m + 8.f)) {          // T13 defer-max
      const float mn = fmaxf(m, pm);
      const float scl = __builtin_amdgcn_exp2f((m - mn) * LOG2E);
      m = mn;
      lsum *= scl;
      Ssc[wid][l31] = scl;
      f32x4 s0 = *(const f32x4*)&Ssc[wid][hi * 4];
      f32x4 s1 = *(const f32x4*)&Ssc[wid][8 + hi * 4];
      f32x4 s2 = *(const f32x4*)&Ssc[wid][16 + hi * 4];
      f32x4 s3 = *(const f32x4*)&Ssc[wid][24 + hi * 4];
#pragma unroll
      for (int r = 0; r < 16; ++r) {
        const float sv = (r < 4 ? s0[r & 3] : r < 8 ? s1[r & 3] : r < 12 ? s2[r & 3] : s3[r & 3]);
        o0[r] *= sv; o1[r] *= sv;
      }
    }

    const float nml = -m * LOG2E;
#pragma unroll
    for (int r = 0; r < 16; ++r)
      P0[r] = __builtin_amdgcn_exp2f(__builtin_fmaf(P0[r], LOG2E, nml));
#pragma unroll
    for (int r = 0; r < 16; ++r)
      P1[r] = __builtin_amdgcn_exp2f(__builtin_fmaf(P1[r], LOG2E, nml));

    float rs = 0.f;
#pragma unroll
    for (int r = 0; r < 16; ++r) rs += P0[r] + P1[r];
    rs += __shfl_xor(rs, 32);             // cross-half merge (validated path)
    lsum += rs;

    bf16x8 pa[4];
#pragma unroll
    for (int s = 0; s < 2; ++s) {
      const f32x16& P = s ? P1 : P0;
      uint a0 = cvtpk(P[0], P[1]),  b0 = cvtpk(P[4], P[5]);
      uint a1 = cvtpk(P[2], P[3]),  b1 = cvtpk(P[6], P[7]);
      plswap(a0, b0); plswap(a1, b1);
      pa[2 * s] = __builtin_bit_cast(bf16x8, (u32x4){a0, a1, b0, b1});
      uint a2 = cvtpk(P[8], P[9]),   b2 = cvtpk(P[12], P[13]);
      uint a3 = cvtpk(P[10], P[11]), b3 = cvtpk(P[14], P[15]);
      plswap(a2, b2); plswap(a3, b3);
      pa[2 * s + 1] = __builtin_bit_cast(bf16x8, (u32x4){a2, a3, b2, b3});
    }

    __builtin_amdgcn_s_setprio(1);
#pragma unroll
    for (int kk = 0; kk < 4; ++kk) {
      bf16x8 v0f = *(const bf16x8*)(Vsh[cur] + swz(l31,      kk * 32 + hi * 16));
      bf16x8 v1f = *(const bf16x8*)(Vsh[cur] + swz(32 + l31, kk * 32 + hi * 16));
      o0 = mfma32(pa[kk], v0f, o0);
      o1 = mfma32(pa[kk], v1f, o1);
    }
    __builtin_amdgcn_s_setprio(0);

    if (t + 1 < 32) {
      // write-late into the idle buffer; readers of buf[cur^1] (iter t-1)
      // all finished before the barrier at end of iter t-1.
      *(u16x8*)(Ksh[cur ^ 1] + swz(si, sc4i * 32))      = kr0;
      *(u16x8*)(Ksh[cur ^ 1] + swz(si, sc4i * 32 + 16)) = kr1;
      *(u16x8*)(Vsh[cur ^ 1] + swz(si, sc4i * 32))      = vr0;
      *(u16x8*)(Vsh[cur ^ 1] + swz(si, sc4i * 32 + 16)) = vr1;
      __syncthreads();   // single barrier per tile
    }
  }

  Ssc[wid][l31] = 1.0f / lsum;
  f32x4 i0 = *(const f32x4*)&Ssc[wid][hi * 4];
  f32x4 i1 = *(const f32x4*)&Ssc[wid][8 + hi * 4];
  f32x4 i2 = *(const f32x4*)&Ssc[wid][16 + hi * 4];
  f32x4 i3 = *(const f32x4*)&Ssc[wid][24 + hi * 4];
  const int b = bh >> 4, h = bh & 15;
#pragma unroll
  for (int r = 0; r < 16; ++r) {
    const float inv = (r < 4 ? i0[r & 3] : r < 8 ? i1[r & 3] : r < 12 ? i2[r & 3] : i3[r & 3]);
    const int q = q0 + (r & 3) + 8 * (r >> 2) + 4 * hi;
    const size_t base = ((size_t)(b * 2048 + q)) * 1024 + h * 64;
    ctxb[base + l31]      = f2bf(o0[r] * inv);
    ctxb[base + 32 + l31] = f2bf(o1[r] * inv);
  }
}

// ---------------- output projection: 64x128 tile, BK=64, swizzled (R15) ----
__global__ __launch_bounds__(256) void out_gemm(const ushort* __restrict__ A16,
                                                const ushort* __restrict__ Wb,
                                                const float* __restrict__ bias,
                                                float* __restrict__ O) {
  __shared__ ushort Ash[64 * 64];    // 8 KB, 8 chunks
  __shared__ ushort Bsh[128 * 64];   // 16 KB, 16 chunks

  const int tid = threadIdx.x;
  const int lane = tid & 63, wid = tid >> 6;
  const int l15 = lane & 15, g = lane >> 4;
  const int wr = wid >> 1, wc = wid & 1;
  const int tm = blockIdx.x * 64, tn = blockIdx.y * 128;

  const f32x4 fz = {0.f, 0.f, 0.f, 0.f};
  f32x4 acc[2][4];
#pragma unroll
  for (int m = 0; m < 2; ++m)
#pragma unroll
    for (int n = 0; n < 4; ++n) acc[m][n] = fz;

  const int srow8 = lane >> 3;
  const int ssl   = (lane & 7) ^ srow8;

  for (int kt = 0; kt < 1024; kt += 64) {
#pragma unroll
    for (int c = 0; c < 4; ++c) {
      const int chunk = wid * 4 + c;           // B: 16 chunks of 8 rows
      const int row = chunk * 8 + srow8;
      gload16(Wb + (size_t)(tn + row) * 1024 + kt + ssl * 8, &Bsh[chunk * 512]);
    }
#pragma unroll
    for (int c = 0; c < 2; ++c) {
      const int chunk = wid * 2 + c;           // A: 8 chunks of 8 rows
      const int row = chunk * 8 + srow8;
      gload16(A16 + (size_t)(tm + row) * 1024 + kt + ssl * 8, &Ash[chunk * 512]);
    }
    __syncthreads();

#pragma unroll
    for (int kk = 0; kk < 2; ++kk) {
      bf16x8 af[2], bfr[4];
#pragma unroll
      for (int m = 0; m < 2; ++m) {
        const int row = wr * 32 + m * 16 + l15;
        af[m] = *(const bf16x8*)&Ash[row * 64 + (((kk * 4 + g) ^ (row & 7)) * 8)];
      }
#pragma unroll
      for (int n = 0; n < 4; ++n) {
        const int row = wc * 64 + n * 16 + l15;
        bfr[n] = *(const bf16x8*)&Bsh[row * 64 + (((kk * 4 + g) ^ (row & 7)) * 8)];
      }
#pragma unroll
      for (int m = 0; m < 2; ++m)
#pragma unroll
        for (int n = 0; n < 4; ++n) acc[m][n] = mfma16(af[m], bfr[n], acc[m][n]);
    }
    __syncthreads();
  }

#pragma unroll
  for (int n = 0; n < 4; ++n) {
    const int col = tn + wc * 64 + n * 16 + l15;
    const float bv = bias[col];
#pragma unroll
    for (int m = 0; m < 2; ++m) {
      const int row0 = tm + wr * 32 + m * 16 + g * 4;
#pragma unroll
      for (int r = 0; r < 4; ++r)
        O[(size_t)(row0 + r) * 1024 + col] = acc[m][n][r] + bv;
    }
  }
}

extern "C" void kernel_launch(void* const* d_in, const int* in_sizes, int n_in,
                              void* d_out, int out_size, void* d_ws, size_t ws_size,
                              hipStream_t stream) {
  const float* query = (const float*)d_in[0];
  const float* key_  = (const float*)d_in[1];
  const float* value = (const float*)d_in[2];
  const float* Wq = (const float*)d_in[3];
  const float* bq = (const float*)d_in[4];
  const float* Wk = (const float*)d_in[5];
  const float* bk = (const float*)d_in[6];
  const float* Wv = (const float*)d_in[7];
  const float* bv = (const float*)d_in[8];
  const float* Wo = (const float*)d_in[9];
  const float* bo = (const float*)d_in[10];

  ushort* ws = (ushort*)d_ws;
  ushort* Wqb = ws;                       // 1M elems each
  ushort* Wkb = ws + (1u << 20);
  ushort* Wvb = ws + (2u << 20);
  ushort* Wob = ws + (3u << 20);
  ushort* Qb  = ws + (4u << 20);          // 4M elems each
  ushort* Kb  = Qb + (4u << 20);
  ushort* VTb = Kb + (4u << 20);
  ushort* ctx = VTb + (4u << 20);         // 4M elems; doubles as Xq scratch
  ushort* Xqb = ctx;
  ushort* Xkb = (ushort*)d_out;           // dead after qkv
  ushort* Xvb = (ushort*)d_out + (4u << 20);

  dim3 blk(256);

  CvtArgs ca;
  ca.src[0] = Wq;    ca.dst[0] = Wqb;
  ca.src[1] = Wk;    ca.dst[1] = Wkb;
  ca.src[2] = Wv;    ca.dst[2] = Wvb;
  ca.src[3] = Wo;    ca.dst[3] = Wob;
  ca.src[4] = query; ca.dst[4] = Xqb;
  ca.src[5] = key_;  ca.dst[5] = Xkb;
  ca.src[6] = value; ca.dst[6] = Xvb;
  cvt_all<<<8192, blk, 0, stream>>>(ca);

  QKVArgs a;
  a.A0 = Xqb;  a.A1 = Xkb;  a.A2 = Xvb;
  a.W0 = Wqb;  a.W1 = Wkb;  a.W2 = Wvb;
  a.b0 = bq;   a.b1 = bk;   a.b2 = bv;
  a.Qo = Qb;   a.Ko = Kb;   a.Vo = VTb;
  qkv_gemm<<<dim3(32, 8, 3), blk, 0, stream>>>(a);

  attn_fwd<<<dim3(16, 32), blk, 0, stream>>>(Qb, Kb, VTb, ctx);

  out_gemm<<<dim3(64, 8), blk, 0, stream>>>(ctx, Wob, bo, (float*)d_out);
}

// Round 17
// 131.012 us; speedup vs baseline: 1.0129x; 1.0129x over previous
//
#include <hip/hip_runtime.h>
#include <stdint.h>

typedef __attribute__((ext_vector_type(8)))  __bf16 bf16x8;
typedef __attribute__((ext_vector_type(4)))  float  f32x4;
typedef __attribute__((ext_vector_type(16))) float  f32x16;
typedef __attribute__((ext_vector_type(8)))  ushort u16x8;
typedef __attribute__((ext_vector_type(4)))  ushort u16x4;
typedef __attribute__((ext_vector_type(4)))  uint   u32x4;

#define LOG2E 1.44269504088896f

__device__ __forceinline__ ushort f2bf(float f) {
  uint32_t u = __float_as_uint(f);
  u += 0x7fffu + ((u >> 16) & 1u);   // RNE
  return (ushort)(u >> 16);
}
__device__ __forceinline__ float bf2f(ushort h) {
  return __uint_as_float(((uint32_t)h) << 16);
}
__device__ __forceinline__ void gload16(const void* g, void* l) {
  __builtin_amdgcn_global_load_lds((const __attribute__((address_space(1))) void*)g,
                                   (__attribute__((address_space(3))) void*)l, 16, 0, 0);
}
__device__ __forceinline__ f32x4 mfma16(bf16x8 a, bf16x8 b, f32x4 c) {
  return __builtin_amdgcn_mfma_f32_16x16x32_bf16(a, b, c, 0, 0, 0);
}
__device__ __forceinline__ f32x16 mfma32(bf16x8 a, bf16x8 b, f32x16 c) {
  return __builtin_amdgcn_mfma_f32_32x32x16_bf16(a, b, c, 0, 0, 0);
}
// LDS XOR swizzle for 128B rows (m214 G4): byte ^= (row&7)<<4
__device__ __forceinline__ int swz(int row, int byteoff) {
  return row * 128 + (byteoff ^ ((row & 7) << 4));
}
__device__ __forceinline__ uint cvtpk(float lo, float hi) {
  uint w;
  asm("v_cvt_pk_bf16_f32 %0, %1, %2" : "=v"(w) : "v"(lo), "v"(hi));
  return w;
}
__device__ __forceinline__ void plswap(uint& a, uint& b) {
  asm("v_permlane32_swap_b32 %0, %1" : "+v"(a), "+v"(b));
}
// NOTE (R7/R8): permlane cross-half merge idiom FAILED on HW twice (~6e-2).
// NOTE (R11): split-KV (2x blocks) = ZERO attn speedup (throughput-bound).
// NOTE (R13): gload_lds+dbuf attn staging = +13% REGRESSION vs reg-staging.
// NOTE (R14): no-max softmax = null; attn is issue-port saturated.
// NOTE (R16): attn dbuf/1-barrier = null. attn is at its structural floor
// (~57.5us) after 5 experiments; frozen at the R15 form.
// NOTE (R17): qkv T3-minimum-2-phase — dbuf + prefetch-before-compute +
// single barrier/K-step; the vmcnt(0) drain is covered by the compute phase
// (qkv was stage-and-drain; R13's lesson was about replacing reg-staging,
// which qkv never had).

// ---------------- batched fp32 -> bf16 (weights + activations), ONE launch ----
struct CvtArgs { const float* src[7]; ushort* dst[7]; };

__global__ __launch_bounds__(256) void cvt_all(CvtArgs a) {
  const int bid = blockIdx.x;
  int seg, base;
  if (bid < 2048) { seg = bid >> 9;              base = bid & 511; }
  else            { seg = 4 + ((bid - 2048) >> 11); base = (bid - 2048) & 2047; }
  const int i = base * 256 + threadIdx.x;   // n8 index
  const f32x4* s = (const f32x4*)a.src[seg];
  f32x4 x = s[2 * i], y = s[2 * i + 1];
  u16x8 o;
  o[0] = f2bf(x[0]); o[1] = f2bf(x[1]); o[2] = f2bf(x[2]); o[3] = f2bf(x[3]);
  o[4] = f2bf(y[0]); o[5] = f2bf(y[1]); o[6] = f2bf(y[2]); o[7] = f2bf(y[3]);
  ((u16x8*)a.dst[seg])[i] = o;
}

// ---------------- QKV projection GEMM: bf16, BK=64, swizzled, 2-phase dbuf ----
struct QKVArgs {
  const ushort* A0; const ushort* A1; const ushort* A2;
  const ushort* W0; const ushort* W1; const ushort* W2;
  const float* b0; const float* b1; const float* b2;
  ushort* Qo; ushort* Ko; ushort* Vo;
};

__global__ __launch_bounds__(256) void qkv_gemm(QKVArgs args) {
  __shared__ ushort Ash[2][128 * 64];   // 32 KB
  __shared__ ushort Bsh[2][128 * 64];   // 32 KB

  const int z = blockIdx.z;
  const ushort* Ab   = z == 0 ? args.A0 : (z == 1 ? args.A1 : args.A2);
  const ushort* Wb   = z == 0 ? args.W0 : (z == 1 ? args.W1 : args.W2);
  const float*  bias = z == 0 ? args.b0 : (z == 1 ? args.b1 : args.b2);

  const int tid = threadIdx.x;
  const int lane = tid & 63, wid = tid >> 6;
  const int l15 = lane & 15, g = lane >> 4;
  const int wr = wid >> 1, wc = wid & 1;
  const int tm = blockIdx.x * 128, tn = blockIdx.y * 128;

  const f32x4 fz = {0.f, 0.f, 0.f, 0.f};
  f32x4 acc[4][4];
#pragma unroll
  for (int m = 0; m < 4; ++m)
#pragma unroll
    for (int n = 0; n < 4; ++n) acc[m][n] = fz;

  const int srow8 = lane >> 3;                 // row within 8-row chunk
  const int ssl   = (lane & 7) ^ srow8;        // pre-swizzled source slot

#define QSTAGE(buf, kt)                                                       \
  {                                                                           \
    _Pragma("unroll")                                                         \
    for (int c = 0; c < 4; ++c) {                                             \
      const int chunk = wid * 4 + c;                                          \
      const int row = chunk * 8 + srow8;                                      \
      gload16(Wb + (size_t)(tn + row) * 1024 + (kt) + ssl * 8,                \
              &Bsh[buf][chunk * 512]);                                        \
      gload16(Ab + (size_t)(tm + row) * 1024 + (kt) + ssl * 8,                \
              &Ash[buf][chunk * 512]);                                        \
    }                                                                         \
  }

  QSTAGE(0, 0);
  __syncthreads();                             // prologue drain

  for (int kt = 0, t = 0; kt < 1024; kt += 64, ++t) {
    const int cur = t & 1;
    if (kt + 64 < 1024) QSTAGE(cur ^ 1, kt + 64);   // prefetch next K-step

#pragma unroll
    for (int kk = 0; kk < 2; ++kk) {
      bf16x8 af[4], bfr[4];
#pragma unroll
      for (int m = 0; m < 4; ++m) {
        const int row = wr * 64 + m * 16 + l15;
        af[m] = *(const bf16x8*)&Ash[cur][row * 64 + (((kk * 4 + g) ^ (row & 7)) * 8)];
      }
#pragma unroll
      for (int n = 0; n < 4; ++n) {
        const int row = wc * 64 + n * 16 + l15;
        bfr[n] = *(const bf16x8*)&Bsh[cur][row * 64 + (((kk * 4 + g) ^ (row & 7)) * 8)];
      }
#pragma unroll
      for (int m = 0; m < 4; ++m)
#pragma unroll
        for (int n = 0; n < 4; ++n) acc[m][n] = mfma16(af[m], bfr[n], acc[m][n]);
    }

    if (kt + 64 < 1024) __syncthreads();       // single barrier: drains prefetch,
                                               // releases buf[cur] for restaging
  }
#undef QSTAGE

#pragma unroll
  for (int n = 0; n < 4; ++n) {
    const int col = tn + wc * 64 + n * 16 + l15;
    const float bv = bias[col];
    const int h = col >> 6, d = col & 63;
#pragma unroll
    for (int m = 0; m < 4; ++m) {
      const int row0 = tm + wr * 64 + m * 16 + g * 4;
      if (z == 2) {            // V^T : [B,H,Dh,S]
        const int b = row0 >> 11, s0 = row0 & 2047;
        u16x4 pk;
#pragma unroll
        for (int r = 0; r < 4; ++r) pk[r] = f2bf(acc[m][n][r] + bv);
        *(u16x4*)&args.Vo[((size_t)((b * 16 + h) * 64 + d)) * 2048 + s0] = pk;
      } else {                 // Q/K : [B,H,S,Dh]
        ushort* O = z ? args.Ko : args.Qo;
#pragma unroll
        for (int r = 0; r < 4; ++r) {
          const int row = row0 + r;
          const int b = row >> 11, s = row & 2047;
          O[((size_t)(b * 16 + h) * 2048 + s) * 64 + d] = f2bf(acc[m][n][r] + bv);
        }
      }
    }
  }
}

// ---------------- flash attention (R15-exact: frozen at structural floor) ----
__global__ __launch_bounds__(256) void attn_fwd(const ushort* __restrict__ Qb,
                                                const ushort* __restrict__ Kb,
                                                const ushort* __restrict__ VTb,
                                                ushort* __restrict__ ctxb) {
  __shared__ char Ksh[64 * 128];
  __shared__ char Vsh[64 * 128];
  __shared__ float Ssc[4][32];

  const int tid = threadIdx.x;
  const int lane = tid & 63, wid = tid >> 6;
  const int l31 = lane & 31, hi = lane >> 5;
  const int bh = blockIdx.y;
  const int q0 = blockIdx.x * 128 + wid * 32;

  const ushort* Qh = Qb + (size_t)bh * 2048 * 64;
  const ushort* Kh = Kb + (size_t)bh * 2048 * 64;
  const ushort* Vh = VTb + (size_t)bh * 64 * 2048;

  bf16x8 qf[4];
  {
    const ushort* qrow = Qh + (size_t)(q0 + l31) * 64;
#pragma unroll
    for (int dt = 0; dt < 4; ++dt) {
      u16x8 raw = *(const u16x8*)&qrow[dt * 16 + hi * 8];
      u16x8 sc;
#pragma unroll
      for (int j = 0; j < 8; ++j) sc[j] = f2bf(bf2f(raw[j]) * 0.125f);
      qf[dt] = __builtin_bit_cast(bf16x8, sc);
    }
  }

  f32x16 o0 = {}, o1 = {};
  float m = -1e30f, lsum = 0.f;

  const int si = tid >> 2, sc4i = tid & 3;
  const ushort* kg = &Kh[(size_t)si * 64 + sc4i * 16];
  const ushort* vg = &Vh[(size_t)si * 2048 + sc4i * 16];

  u16x8 kr0, kr1, vr0, vr1;
  kr0 = *(const u16x8*)kg;  kr1 = *(const u16x8*)(kg + 8);
  vr0 = *(const u16x8*)vg;  vr1 = *(const u16x8*)(vg + 8);
  *(u16x8*)(Ksh + swz(si, sc4i * 32))      = kr0;
  *(u16x8*)(Ksh + swz(si, sc4i * 32 + 16)) = kr1;
  *(u16x8*)(Vsh + swz(si, sc4i * 32))      = vr0;
  *(u16x8*)(Vsh + swz(si, sc4i * 32 + 16)) = vr1;
  __syncthreads();

  for (int t = 0; t < 32; ++t) {
    if (t + 1 < 32) {
      const int kt2 = (t + 1) * 64;
      kr0 = *(const u16x8*)(kg + (size_t)kt2 * 64);
      kr1 = *(const u16x8*)(kg + (size_t)kt2 * 64 + 8);
      vr0 = *(const u16x8*)(vg + kt2);
      vr1 = *(const u16x8*)(vg + kt2 + 8);
    }

    f32x16 P0 = {}, P1 = {};
    __builtin_amdgcn_s_setprio(1);
#pragma unroll
    for (int dt = 0; dt < 4; ++dt) {
      bf16x8 kf0 = *(const bf16x8*)(Ksh + swz(l31,      dt * 32 + hi * 16));
      bf16x8 kf1 = *(const bf16x8*)(Ksh + swz(32 + l31, dt * 32 + hi * 16));
      P0 = mfma32(kf0, qf[dt], P0);
      P1 = mfma32(kf1, qf[dt], P1);
    }
    __builtin_amdgcn_s_setprio(0);

    // local max via v_max3 chains (exact reassociation)
    float pm = fmaxf(P0[0], P1[0]);
#pragma unroll
    for (int r = 1; r + 1 < 16; r += 2) {
      pm = fmaxf(fmaxf(pm, P0[r]), P0[r + 1]);
      pm = fmaxf(fmaxf(pm, P1[r]), P1[r + 1]);
    }
    pm = fmaxf(fmaxf(pm, P0[15]), P1[15]);
    pm = fmaxf(pm, __shfl_xor(pm, 32));   // cross-half merge (validated path)

    if (!__all(pm <= m + 8.f)) {          // T13 defer-max
      const float mn = fmaxf(m, pm);
      const float scl = __builtin_amdgcn_exp2f((m - mn) * LOG2E);
      m = mn;
      lsum *= scl;
      Ssc[wid][l31] = scl;
      f32x4 s0 = *(const f32x4*)&Ssc[wid][hi * 4];
      f32x4 s1 = *(const f32x4*)&Ssc[wid][8 + hi * 4];
      f32x4 s2 = *(const f32x4*)&Ssc[wid][16 + hi * 4];
      f32x4 s3 = *(const f32x4*)&Ssc[wid][24 + hi * 4];
#pragma unroll
      for (int r = 0; r < 16; ++r) {
        const float sv = (r < 4 ? s0[r & 3] : r < 8 ? s1[r & 3] : r < 12 ? s2[r & 3] : s3[r & 3]);
        o0[r] *= sv; o1[r] *= sv;
      }
    }

    const float nml = -m * LOG2E;
#pragma unroll
    for (int r = 0; r < 16; ++r)
      P0[r] = __builtin_amdgcn_exp2f(__builtin_fmaf(P0[r], LOG2E, nml));
#pragma unroll
    for (int r = 0; r < 16; ++r)
      P1[r] = __builtin_amdgcn_exp2f(__builtin_fmaf(P1[r], LOG2E, nml));

    float rs = 0.f;
#pragma unroll
    for (int r = 0; r < 16; ++r) rs += P0[r] + P1[r];
    rs += __shfl_xor(rs, 32);             // cross-half merge (validated path)
    lsum += rs;

    bf16x8 pa[4];
#pragma unroll
    for (int s = 0; s < 2; ++s) {
      const f32x16& P = s ? P1 : P0;
      uint a0 = cvtpk(P[0], P[1]),  b0 = cvtpk(P[4], P[5]);
      uint a1 = cvtpk(P[2], P[3]),  b1 = cvtpk(P[6], P[7]);
      plswap(a0, b0); plswap(a1, b1);
      pa[2 * s] = __builtin_bit_cast(bf16x8, (u32x4){a0, a1, b0, b1});
      uint a2 = cvtpk(P[8], P[9]),   b2 = cvtpk(P[12], P[13]);
      uint a3 = cvtpk(P[10], P[11]), b3 = cvtpk(P[14], P[15]);
      plswap(a2, b2); plswap(a3, b3);
      pa[2 * s + 1] = __builtin_bit_cast(bf16x8, (u32x4){a2, a3, b2, b3});
    }

    __builtin_amdgcn_s_setprio(1);
#pragma unroll
    for (int kk = 0; kk < 4; ++kk) {
      bf16x8 v0f = *(const bf16x8*)(Vsh + swz(l31,      kk * 32 + hi * 16));
      bf16x8 v1f = *(const bf16x8*)(Vsh + swz(32 + l31, kk * 32 + hi * 16));
      o0 = mfma32(pa[kk], v0f, o0);
      o1 = mfma32(pa[kk], v1f, o1);
    }
    __builtin_amdgcn_s_setprio(0);

    if (t + 1 < 32) {
      __syncthreads();
      *(u16x8*)(Ksh + swz(si, sc4i * 32))      = kr0;
      *(u16x8*)(Ksh + swz(si, sc4i * 32 + 16)) = kr1;
      *(u16x8*)(Vsh + swz(si, sc4i * 32))      = vr0;
      *(u16x8*)(Vsh + swz(si, sc4i * 32 + 16)) = vr1;
      __syncthreads();
    }
  }

  Ssc[wid][l31] = 1.0f / lsum;
  f32x4 i0 = *(const f32x4*)&Ssc[wid][hi * 4];
  f32x4 i1 = *(const f32x4*)&Ssc[wid][8 + hi * 4];
  f32x4 i2 = *(const f32x4*)&Ssc[wid][16 + hi * 4];
  f32x4 i3 = *(const f32x4*)&Ssc[wid][24 + hi * 4];
  const int b = bh >> 4, h = bh & 15;
#pragma unroll
  for (int r = 0; r < 16; ++r) {
    const float inv = (r < 4 ? i0[r & 3] : r < 8 ? i1[r & 3] : r < 12 ? i2[r & 3] : i3[r & 3]);
    const int q = q0 + (r & 3) + 8 * (r >> 2) + 4 * hi;
    const size_t base = ((size_t)(b * 2048 + q)) * 1024 + h * 64;
    ctxb[base + l31]      = f2bf(o0[r] * inv);
    ctxb[base + 32 + l31] = f2bf(o1[r] * inv);
  }
}

// ---------------- output projection: 64x128 tile, BK=64, swizzled (R15) ----
__global__ __launch_bounds__(256) void out_gemm(const ushort* __restrict__ A16,
                                                const ushort* __restrict__ Wb,
                                                const float* __restrict__ bias,
                                                float* __restrict__ O) {
  __shared__ ushort Ash[64 * 64];    // 8 KB, 8 chunks
  __shared__ ushort Bsh[128 * 64];   // 16 KB, 16 chunks

  const int tid = threadIdx.x;
  const int lane = tid & 63, wid = tid >> 6;
  const int l15 = lane & 15, g = lane >> 4;
  const int wr = wid >> 1, wc = wid & 1;
  const int tm = blockIdx.x * 64, tn = blockIdx.y * 128;

  const f32x4 fz = {0.f, 0.f, 0.f, 0.f};
  f32x4 acc[2][4];
#pragma unroll
  for (int m = 0; m < 2; ++m)
#pragma unroll
    for (int n = 0; n < 4; ++n) acc[m][n] = fz;

  const int srow8 = lane >> 3;
  const int ssl   = (lane & 7) ^ srow8;

  for (int kt = 0; kt < 1024; kt += 64) {
#pragma unroll
    for (int c = 0; c < 4; ++c) {
      const int chunk = wid * 4 + c;           // B: 16 chunks of 8 rows
      const int row = chunk * 8 + srow8;
      gload16(Wb + (size_t)(tn + row) * 1024 + kt + ssl * 8, &Bsh[chunk * 512]);
    }
#pragma unroll
    for (int c = 0; c < 2; ++c) {
      const int chunk = wid * 2 + c;           // A: 8 chunks of 8 rows
      const int row = chunk * 8 + srow8;
      gload16(A16 + (size_t)(tm + row) * 1024 + kt + ssl * 8, &Ash[chunk * 512]);
    }
    __syncthreads();

#pragma unroll
    for (int kk = 0; kk < 2; ++kk) {
      bf16x8 af[2], bfr[4];
#pragma unroll
      for (int m = 0; m < 2; ++m) {
        const int row = wr * 32 + m * 16 + l15;
        af[m] = *(const bf16x8*)&Ash[row * 64 + (((kk * 4 + g) ^ (row & 7)) * 8)];
      }
#pragma unroll
      for (int n = 0; n < 4; ++n) {
        const int row = wc * 64 + n * 16 + l15;
        bfr[n] = *(const bf16x8*)&Bsh[row * 64 + (((kk * 4 + g) ^ (row & 7)) * 8)];
      }
#pragma unroll
      for (int m = 0; m < 2; ++m)
#pragma unroll
        for (int n = 0; n < 4; ++n) acc[m][n] = mfma16(af[m], bfr[n], acc[m][n]);
    }
    __syncthreads();
  }

#pragma unroll
  for (int n = 0; n < 4; ++n) {
    const int col = tn + wc * 64 + n * 16 + l15;
    const float bv = bias[col];
#pragma unroll
    for (int m = 0; m < 2; ++m) {
      const int row0 = tm + wr * 32 + m * 16 + g * 4;
#pragma unroll
      for (int r = 0; r < 4; ++r)
        O[(size_t)(row0 + r) * 1024 + col] = acc[m][n][r] + bv;
    }
  }
}

extern "C" void kernel_launch(void* const* d_in, const int* in_sizes, int n_in,
                              void* d_out, int out_size, void* d_ws, size_t ws_size,
                              hipStream_t stream) {
  const float* query = (const float*)d_in[0];
  const float* key_  = (const float*)d_in[1];
  const float* value = (const float*)d_in[2];
  const float* Wq = (const float*)d_in[3];
  const float* bq = (const float*)d_in[4];
  const float* Wk = (const float*)d_in[5];
  const float* bk = (const float*)d_in[6];
  const float* Wv = (const float*)d_in[7];
  const float* bv = (const float*)d_in[8];
  const float* Wo = (const float*)d_in[9];
  const float* bo = (const float*)d_in[10];

  ushort* ws = (ushort*)d_ws;
  ushort* Wqb = ws;                       // 1M elems each
  ushort* Wkb = ws + (1u << 20);
  ushort* Wvb = ws + (2u << 20);
  ushort* Wob = ws + (3u << 20);
  ushort* Qb  = ws + (4u << 20);          // 4M elems each
  ushort* Kb  = Qb + (4u << 20);
  ushort* VTb = Kb + (4u << 20);
  ushort* ctx = VTb + (4u << 20);         // 4M elems; doubles as Xq scratch
  ushort* Xqb = ctx;
  ushort* Xkb = (ushort*)d_out;           // dead after qkv
  ushort* Xvb = (ushort*)d_out + (4u << 20);

  dim3 blk(256);

  CvtArgs ca;
  ca.src[0] = Wq;    ca.dst[0] = Wqb;
  ca.src[1] = Wk;    ca.dst[1] = Wkb;
  ca.src[2] = Wv;    ca.dst[2] = Wvb;
  ca.src[3] = Wo;    ca.dst[3] = Wob;
  ca.src[4] = query; ca.dst[4] = Xqb;
  ca.src[5] = key_;  ca.dst[5] = Xkb;
  ca.src[6] = value; ca.dst[6] = Xvb;
  cvt_all<<<8192, blk, 0, stream>>>(ca);

  QKVArgs a;
  a.A0 = Xqb;  a.A1 = Xkb;  a.A2 = Xvb;
  a.W0 = Wqb;  a.W1 = Wkb;  a.W2 = Wvb;
  a.b0 = bq;   a.b1 = bk;   a.b2 = bv;
  a.Qo = Qb;   a.Ko = Kb;   a.Vo = VTb;
  qkv_gemm<<<dim3(32, 8, 3), blk, 0, stream>>>(a);

  attn_fwd<<<dim3(16, 32), blk, 0, stream>>>(Qb, Kb, VTb, ctx);

  out_gemm<<<dim3(64, 8), blk, 0, stream>>>(ctx, Wob, bo, (float*)d_out);
}

// Round 18
// 123.943 us; speedup vs baseline: 1.0707x; 1.0570x over previous
//
#include <hip/hip_runtime.h>
#include <stdint.h>

typedef __attribute__((ext_vector_type(8)))  __bf16 bf16x8;
typedef __attribute__((ext_vector_type(4)))  float  f32x4;
typedef __attribute__((ext_vector_type(16))) float  f32x16;
typedef __attribute__((ext_vector_type(8)))  ushort u16x8;
typedef __attribute__((ext_vector_type(4)))  ushort u16x4;
typedef __attribute__((ext_vector_type(4)))  uint   u32x4;

#define LOG2E 1.44269504088896f

__device__ __forceinline__ ushort f2bf(float f) {
  uint32_t u = __float_as_uint(f);
  u += 0x7fffu + ((u >> 16) & 1u);   // RNE
  return (ushort)(u >> 16);
}
__device__ __forceinline__ float bf2f(ushort h) {
  return __uint_as_float(((uint32_t)h) << 16);
}
__device__ __forceinline__ void gload16(const void* g, void* l) {
  __builtin_amdgcn_global_load_lds((const __attribute__((address_space(1))) void*)g,
                                   (__attribute__((address_space(3))) void*)l, 16, 0, 0);
}
__device__ __forceinline__ f32x4 mfma16(bf16x8 a, bf16x8 b, f32x4 c) {
  return __builtin_amdgcn_mfma_f32_16x16x32_bf16(a, b, c, 0, 0, 0);
}
__device__ __forceinline__ f32x16 mfma32(bf16x8 a, bf16x8 b, f32x16 c) {
  return __builtin_amdgcn_mfma_f32_32x32x16_bf16(a, b, c, 0, 0, 0);
}
// LDS XOR swizzle for 128B rows (m214 G4): byte ^= (row&7)<<4
__device__ __forceinline__ int swz(int row, int byteoff) {
  return row * 128 + (byteoff ^ ((row & 7) << 4));
}
__device__ __forceinline__ uint cvtpk(float lo, float hi) {
  uint w;
  asm("v_cvt_pk_bf16_f32 %0, %1, %2" : "=v"(w) : "v"(lo), "v"(hi));
  return w;
}
__device__ __forceinline__ void plswap(uint& a, uint& b) {
  asm("v_permlane32_swap_b32 %0, %1" : "+v"(a), "+v"(b));
}
// NOTE (R7/R8): permlane cross-half merge idiom FAILED on HW twice (~6e-2).
// NOTE (R11): split-KV (2x blocks) = ZERO attn speedup (throughput-bound).
// NOTE (R13): gload_lds+dbuf attn staging = +13% REGRESSION vs reg-staging.
// NOTE (R14): no-max softmax = null; attn is issue-port saturated.
// NOTE (R16): attn dbuf/1-barrier = null; attn frozen at R15 form (~57.5us).
// NOTE (R17): qkv 2-phase dbuf = small win; __syncthreads still drains vmcnt.
// NOTE (R18): qkv T4 counted-vmcnt — BK=32, 3-stage, s_waitcnt vmcnt(4) +
// raw s_barrier keeps 4 loads in flight across each barrier (m218 lever).
// Stage at iter t targets buf[(t+2)%3] = buffer read at t-1 (safe post-barrier).

// ---------------- batched fp32 -> bf16 (weights + activations), ONE launch ----
struct CvtArgs { const float* src[7]; ushort* dst[7]; };

__global__ __launch_bounds__(256) void cvt_all(CvtArgs a) {
  const int bid = blockIdx.x;
  int seg, base;
  if (bid < 2048) { seg = bid >> 9;              base = bid & 511; }
  else            { seg = 4 + ((bid - 2048) >> 11); base = (bid - 2048) & 2047; }
  const int i = base * 256 + threadIdx.x;   // n8 index
  const f32x4* s = (const f32x4*)a.src[seg];
  f32x4 x = s[2 * i], y = s[2 * i + 1];
  u16x8 o;
  o[0] = f2bf(x[0]); o[1] = f2bf(x[1]); o[2] = f2bf(x[2]); o[3] = f2bf(x[3]);
  o[4] = f2bf(y[0]); o[5] = f2bf(y[1]); o[6] = f2bf(y[2]); o[7] = f2bf(y[3]);
  ((u16x8*)a.dst[seg])[i] = o;
}

// ---------------- QKV projection GEMM: bf16, BK=32, 3-stage counted-vmcnt ----
// LDS tiles [128][32] bf16 (64B rows, 4 slots of 16B). Source slot pre-swizzled
// (l&3)^((row>>1)&3); fragment reads slot g^((row>>1)&3) (R5-validated algebra).
struct QKVArgs {
  const ushort* A0; const ushort* A1; const ushort* A2;
  const ushort* W0; const ushort* W1; const ushort* W2;
  const float* b0; const float* b1; const float* b2;
  ushort* Qo; ushort* Ko; ushort* Vo;
};

__global__ __launch_bounds__(256) void qkv_gemm(QKVArgs args) {
  __shared__ ushort Ash[3][128 * 32];   // 3 x 8 KB
  __shared__ ushort Bsh[3][128 * 32];   // 3 x 8 KB  (48 KB total -> 3 blk/CU)

  const int z = blockIdx.z;
  const ushort* Ab   = z == 0 ? args.A0 : (z == 1 ? args.A1 : args.A2);
  const ushort* Wb   = z == 0 ? args.W0 : (z == 1 ? args.W1 : args.W2);
  const float*  bias = z == 0 ? args.b0 : (z == 1 ? args.b1 : args.b2);

  const int tid = threadIdx.x;
  const int lane = tid & 63, wid = tid >> 6;
  const int l15 = lane & 15, g = lane >> 4;
  const int wr = wid >> 1, wc = wid & 1;
  const int tm = blockIdx.x * 128, tn = blockIdx.y * 128;

  const f32x4 fz = {0.f, 0.f, 0.f, 0.f};
  f32x4 acc[4][4];
#pragma unroll
  for (int m = 0; m < 4; ++m)
#pragma unroll
    for (int n = 0; n < 4; ++n) acc[m][n] = fz;

  // staging: 8 chunks of (16 rows x 64B) per matrix; wave does 2 A + 2 B.
  const int srow16 = lane >> 2;                    // row within 16-row chunk
  const int ssl4   = (lane & 3) ^ ((srow16 >> 1) & 3);  // pre-swizzled slot

#define QSTAGE(buf, kt)                                                       \
  {                                                                           \
    _Pragma("unroll")                                                         \
    for (int c = 0; c < 2; ++c) {                                             \
      const int chunk = wid * 2 + c;                                          \
      const int row = chunk * 16 + srow16;                                    \
      gload16(Wb + (size_t)(tn + row) * 1024 + (kt) + ssl4 * 8,               \
              &Bsh[buf][chunk * 512]);                                        \
      gload16(Ab + (size_t)(tm + row) * 1024 + (kt) + ssl4 * 8,               \
              &Ash[buf][chunk * 512]);                                        \
    }                                                                         \
  }

  QSTAGE(0, 0);
  QSTAGE(1, 32);
  asm volatile("s_waitcnt vmcnt(4)" ::: "memory");   // stage 0 complete
  __builtin_amdgcn_s_barrier();
  __builtin_amdgcn_sched_barrier(0);

#pragma unroll
  for (int t = 0; t < 32; ++t) {
    const int cur = t % 3;
    const int kt = t * 32;
    if (t + 2 < 32) QSTAGE((t + 2) % 3, kt + 64);   // 2-ahead prefetch

    bf16x8 af[4], bfr[4];
#pragma unroll
    for (int m = 0; m < 4; ++m) {
      const int row = wr * 64 + m * 16 + l15;
      af[m] = *(const bf16x8*)&Ash[cur][row * 32 + ((g ^ ((row >> 1) & 3)) * 8)];
    }
#pragma unroll
    for (int n = 0; n < 4; ++n) {
      const int row = wc * 64 + n * 16 + l15;
      bfr[n] = *(const bf16x8*)&Bsh[cur][row * 32 + ((g ^ ((row >> 1) & 3)) * 8)];
    }
#pragma unroll
    for (int m = 0; m < 4; ++m)
#pragma unroll
      for (int n = 0; n < 4; ++n) acc[m][n] = mfma16(af[m], bfr[n], acc[m][n]);

    if (t + 1 < 32) {
      if (t + 2 < 32) asm volatile("s_waitcnt vmcnt(4)" ::: "memory");
      else            asm volatile("s_waitcnt vmcnt(0)" ::: "memory");
      __builtin_amdgcn_s_barrier();
      __builtin_amdgcn_sched_barrier(0);
    }
  }
#undef QSTAGE

#pragma unroll
  for (int n = 0; n < 4; ++n) {
    const int col = tn + wc * 64 + n * 16 + l15;
    const float bv = bias[col];
    const int h = col >> 6, d = col & 63;
#pragma unroll
    for (int m = 0; m < 4; ++m) {
      const int row0 = tm + wr * 64 + m * 16 + g * 4;
      if (z == 2) {            // V^T : [B,H,Dh,S]
        const int b = row0 >> 11, s0 = row0 & 2047;
        u16x4 pk;
#pragma unroll
        for (int r = 0; r < 4; ++r) pk[r] = f2bf(acc[m][n][r] + bv);
        *(u16x4*)&args.Vo[((size_t)((b * 16 + h) * 64 + d)) * 2048 + s0] = pk;
      } else {                 // Q/K : [B,H,S,Dh]
        ushort* O = z ? args.Ko : args.Qo;
#pragma unroll
        for (int r = 0; r < 4; ++r) {
          const int row = row0 + r;
          const int b = row >> 11, s = row & 2047;
          O[((size_t)(b * 16 + h) * 2048 + s) * 64 + d] = f2bf(acc[m][n][r] + bv);
        }
      }
    }
  }
}

// ---------------- flash attention (R15-exact: frozen at structural floor) ----
__global__ __launch_bounds__(256) void attn_fwd(const ushort* __restrict__ Qb,
                                                const ushort* __restrict__ Kb,
                                                const ushort* __restrict__ VTb,
                                                ushort* __restrict__ ctxb) {
  __shared__ char Ksh[64 * 128];
  __shared__ char Vsh[64 * 128];
  __shared__ float Ssc[4][32];

  const int tid = threadIdx.x;
  const int lane = tid & 63, wid = tid >> 6;
  const int l31 = lane & 31, hi = lane >> 5;
  const int bh = blockIdx.y;
  const int q0 = blockIdx.x * 128 + wid * 32;

  const ushort* Qh = Qb + (size_t)bh * 2048 * 64;
  const ushort* Kh = Kb + (size_t)bh * 2048 * 64;
  const ushort* Vh = VTb + (size_t)bh * 64 * 2048;

  bf16x8 qf[4];
  {
    const ushort* qrow = Qh + (size_t)(q0 + l31) * 64;
#pragma unroll
    for (int dt = 0; dt < 4; ++dt) {
      u16x8 raw = *(const u16x8*)&qrow[dt * 16 + hi * 8];
      u16x8 sc;
#pragma unroll
      for (int j = 0; j < 8; ++j) sc[j] = f2bf(bf2f(raw[j]) * 0.125f);
      qf[dt] = __builtin_bit_cast(bf16x8, sc);
    }
  }

  f32x16 o0 = {}, o1 = {};
  float m = -1e30f, lsum = 0.f;

  const int si = tid >> 2, sc4i = tid & 3;
  const ushort* kg = &Kh[(size_t)si * 64 + sc4i * 16];
  const ushort* vg = &Vh[(size_t)si * 2048 + sc4i * 16];

  u16x8 kr0, kr1, vr0, vr1;
  kr0 = *(const u16x8*)kg;  kr1 = *(const u16x8*)(kg + 8);
  vr0 = *(const u16x8*)vg;  vr1 = *(const u16x8*)(vg + 8);
  *(u16x8*)(Ksh + swz(si, sc4i * 32))      = kr0;
  *(u16x8*)(Ksh + swz(si, sc4i * 32 + 16)) = kr1;
  *(u16x8*)(Vsh + swz(si, sc4i * 32))      = vr0;
  *(u16x8*)(Vsh + swz(si, sc4i * 32 + 16)) = vr1;
  __syncthreads();

  for (int t = 0; t < 32; ++t) {
    if (t + 1 < 32) {
      const int kt2 = (t + 1) * 64;
      kr0 = *(const u16x8*)(kg + (size_t)kt2 * 64);
      kr1 = *(const u16x8*)(kg + (size_t)kt2 * 64 + 8);
      vr0 = *(const u16x8*)(vg + kt2);
      vr1 = *(const u16x8*)(vg + kt2 + 8);
    }

    f32x16 P0 = {}, P1 = {};
    __builtin_amdgcn_s_setprio(1);
#pragma unroll
    for (int dt = 0; dt < 4; ++dt) {
      bf16x8 kf0 = *(const bf16x8*)(Ksh + swz(l31,      dt * 32 + hi * 16));
      bf16x8 kf1 = *(const bf16x8*)(Ksh + swz(32 + l31, dt * 32 + hi * 16));
      P0 = mfma32(kf0, qf[dt], P0);
      P1 = mfma32(kf1, qf[dt], P1);
    }
    __builtin_amdgcn_s_setprio(0);

    // local max via v_max3 chains (exact reassociation)
    float pm = fmaxf(P0[0], P1[0]);
#pragma unroll
    for (int r = 1; r + 1 < 16; r += 2) {
      pm = fmaxf(fmaxf(pm, P0[r]), P0[r + 1]);
      pm = fmaxf(fmaxf(pm, P1[r]), P1[r + 1]);
    }
    pm = fmaxf(fmaxf(pm, P0[15]), P1[15]);
    pm = fmaxf(pm, __shfl_xor(pm, 32));   // cross-half merge (validated path)

    if (!__all(pm <= m + 8.f)) {          // T13 defer-max
      const float mn = fmaxf(m, pm);
      const float scl = __builtin_amdgcn_exp2f((m - mn) * LOG2E);
      m = mn;
      lsum *= scl;
      Ssc[wid][l31] = scl;
      f32x4 s0 = *(const f32x4*)&Ssc[wid][hi * 4];
      f32x4 s1 = *(const f32x4*)&Ssc[wid][8 + hi * 4];
      f32x4 s2 = *(const f32x4*)&Ssc[wid][16 + hi * 4];
      f32x4 s3 = *(const f32x4*)&Ssc[wid][24 + hi * 4];
#pragma unroll
      for (int r = 0; r < 16; ++r) {
        const float sv = (r < 4 ? s0[r & 3] : r < 8 ? s1[r & 3] : r < 12 ? s2[r & 3] : s3[r & 3]);
        o0[r] *= sv; o1[r] *= sv;
      }
    }

    const float nml = -m * LOG2E;
#pragma unroll
    for (int r = 0; r < 16; ++r)
      P0[r] = __builtin_amdgcn_exp2f(__builtin_fmaf(P0[r], LOG2E, nml));
#pragma unroll
    for (int r = 0; r < 16; ++r)
      P1[r] = __builtin_amdgcn_exp2f(__builtin_fmaf(P1[r], LOG2E, nml));

    float rs = 0.f;
#pragma unroll
    for (int r = 0; r < 16; ++r) rs += P0[r] + P1[r];
    rs += __shfl_xor(rs, 32);             // cross-half merge (validated path)
    lsum += rs;

    bf16x8 pa[4];
#pragma unroll
    for (int s = 0; s < 2; ++s) {
      const f32x16& P = s ? P1 : P0;
      uint a0 = cvtpk(P[0], P[1]),  b0 = cvtpk(P[4], P[5]);
      uint a1 = cvtpk(P[2], P[3]),  b1 = cvtpk(P[6], P[7]);
      plswap(a0, b0); plswap(a1, b1);
      pa[2 * s] = __builtin_bit_cast(bf16x8, (u32x4){a0, a1, b0, b1});
      uint a2 = cvtpk(P[8], P[9]),   b2 = cvtpk(P[12], P[13]);
      uint a3 = cvtpk(P[10], P[11]), b3 = cvtpk(P[14], P[15]);
      plswap(a2, b2); plswap(a3, b3);
      pa[2 * s + 1] = __builtin_bit_cast(bf16x8, (u32x4){a2, a3, b2, b3});
    }

    __builtin_amdgcn_s_setprio(1);
#pragma unroll
    for (int kk = 0; kk < 4; ++kk) {
      bf16x8 v0f = *(const bf16x8*)(Vsh + swz(l31,      kk * 32 + hi * 16));
      bf16x8 v1f = *(const bf16x8*)(Vsh + swz(32 + l31, kk * 32 + hi * 16));
      o0 = mfma32(pa[kk], v0f, o0);
      o1 = mfma32(pa[kk], v1f, o1);
    }
    __builtin_amdgcn_s_setprio(0);

    if (t + 1 < 32) {
      __syncthreads();
      *(u16x8*)(Ksh + swz(si, sc4i * 32))      = kr0;
      *(u16x8*)(Ksh + swz(si, sc4i * 32 + 16)) = kr1;
      *(u16x8*)(Vsh + swz(si, sc4i * 32))      = vr0;
      *(u16x8*)(Vsh + swz(si, sc4i * 32 + 16)) = vr1;
      __syncthreads();
    }
  }

  Ssc[wid][l31] = 1.0f / lsum;
  f32x4 i0 = *(const f32x4*)&Ssc[wid][hi * 4];
  f32x4 i1 = *(const f32x4*)&Ssc[wid][8 + hi * 4];
  f32x4 i2 = *(const f32x4*)&Ssc[wid][16 + hi * 4];
  f32x4 i3 = *(const f32x4*)&Ssc[wid][24 + hi * 4];
  const int b = bh >> 4, h = bh & 15;
#pragma unroll
  for (int r = 0; r < 16; ++r) {
    const float inv = (r < 4 ? i0[r & 3] : r < 8 ? i1[r & 3] : r < 12 ? i2[r & 3] : i3[r & 3]);
    const int q = q0 + (r & 3) + 8 * (r >> 2) + 4 * hi;
    const size_t base = ((size_t)(b * 2048 + q)) * 1024 + h * 64;
    ctxb[base + l31]      = f2bf(o0[r] * inv);
    ctxb[base + 32 + l31] = f2bf(o1[r] * inv);
  }
}

// ---------------- output projection: 64x128 tile, BK=64, swizzled (R15) ----
__global__ __launch_bounds__(256) void out_gemm(const ushort* __restrict__ A16,
                                                const ushort* __restrict__ Wb,
                                                const float* __restrict__ bias,
                                                float* __restrict__ O) {
  __shared__ ushort Ash[64 * 64];    // 8 KB, 8 chunks
  __shared__ ushort Bsh[128 * 64];   // 16 KB, 16 chunks

  const int tid = threadIdx.x;
  const int lane = tid & 63, wid = tid >> 6;
  const int l15 = lane & 15, g = lane >> 4;
  const int wr = wid >> 1, wc = wid & 1;
  const int tm = blockIdx.x * 64, tn = blockIdx.y * 128;

  const f32x4 fz = {0.f, 0.f, 0.f, 0.f};
  f32x4 acc[2][4];
#pragma unroll
  for (int m = 0; m < 2; ++m)
#pragma unroll
    for (int n = 0; n < 4; ++n) acc[m][n] = fz;

  const int srow8 = lane >> 3;
  const int ssl   = (lane & 7) ^ srow8;

  for (int kt = 0; kt < 1024; kt += 64) {
#pragma unroll
    for (int c = 0; c < 4; ++c) {
      const int chunk = wid * 4 + c;           // B: 16 chunks of 8 rows
      const int row = chunk * 8 + srow8;
      gload16(Wb + (size_t)(tn + row) * 1024 + kt + ssl * 8, &Bsh[chunk * 512]);
    }
#pragma unroll
    for (int c = 0; c < 2; ++c) {
      const int chunk = wid * 2 + c;           // A: 8 chunks of 8 rows
      const int row = chunk * 8 + srow8;
      gload16(A16 + (size_t)(tm + row) * 1024 + kt + ssl * 8, &Ash[chunk * 512]);
    }
    __syncthreads();

#pragma unroll
    for (int kk = 0; kk < 2; ++kk) {
      bf16x8 af[2], bfr[4];
#pragma unroll
      for (int m = 0; m < 2; ++m) {
        const int row = wr * 32 + m * 16 + l15;
        af[m] = *(const bf16x8*)&Ash[row * 64 + (((kk * 4 + g) ^ (row & 7)) * 8)];
      }
#pragma unroll
      for (int n = 0; n < 4; ++n) {
        const int row = wc * 64 + n * 16 + l15;
        bfr[n] = *(const bf16x8*)&Bsh[row * 64 + (((kk * 4 + g) ^ (row & 7)) * 8)];
      }
#pragma unroll
      for (int m = 0; m < 2; ++m)
#pragma unroll
        for (int n = 0; n < 4; ++n) acc[m][n] = mfma16(af[m], bfr[n], acc[m][n]);
    }
    __syncthreads();
  }

#pragma unroll
  for (int n = 0; n < 4; ++n) {
    const int col = tn + wc * 64 + n * 16 + l15;
    const float bv = bias[col];
#pragma unroll
    for (int m = 0; m < 2; ++m) {
      const int row0 = tm + wr * 32 + m * 16 + g * 4;
#pragma unroll
      for (int r = 0; r < 4; ++r)
        O[(size_t)(row0 + r) * 1024 + col] = acc[m][n][r] + bv;
    }
  }
}

extern "C" void kernel_launch(void* const* d_in, const int* in_sizes, int n_in,
                              void* d_out, int out_size, void* d_ws, size_t ws_size,
                              hipStream_t stream) {
  const float* query = (const float*)d_in[0];
  const float* key_  = (const float*)d_in[1];
  const float* value = (const float*)d_in[2];
  const float* Wq = (const float*)d_in[3];
  const float* bq = (const float*)d_in[4];
  const float* Wk = (const float*)d_in[5];
  const float* bk = (const float*)d_in[6];
  const float* Wv = (const float*)d_in[7];
  const float* bv = (const float*)d_in[8];
  const float* Wo = (const float*)d_in[9];
  const float* bo = (const float*)d_in[10];

  ushort* ws = (ushort*)d_ws;
  ushort* Wqb = ws;                       // 1M elems each
  ushort* Wkb = ws + (1u << 20);
  ushort* Wvb = ws + (2u << 20);
  ushort* Wob = ws + (3u << 20);
  ushort* Qb  = ws + (4u << 20);          // 4M elems each
  ushort* Kb  = Qb + (4u << 20);
  ushort* VTb = Kb + (4u << 20);
  ushort* ctx = VTb + (4u << 20);         // 4M elems; doubles as Xq scratch
  ushort* Xqb = ctx;
  ushort* Xkb = (ushort*)d_out;           // dead after qkv
  ushort* Xvb = (ushort*)d_out + (4u << 20);

  dim3 blk(256);

  CvtArgs ca;
  ca.src[0] = Wq;    ca.dst[0] = Wqb;
  ca.src[1] = Wk;    ca.dst[1] = Wkb;
  ca.src[2] = Wv;    ca.dst[2] = Wvb;
  ca.src[3] = Wo;    ca.dst[3] = Wob;
  ca.src[4] = query; ca.dst[4] = Xqb;
  ca.src[5] = key_;  ca.dst[5] = Xkb;
  ca.src[6] = value; ca.dst[6] = Xvb;
  cvt_all<<<8192, blk, 0, stream>>>(ca);

  QKVArgs a;
  a.A0 = Xqb;  a.A1 = Xkb;  a.A2 = Xvb;
  a.W0 = Wqb;  a.W1 = Wkb;  a.W2 = Wvb;
  a.b0 = bq;   a.b1 = bk;   a.b2 = bv;
  a.Qo = Qb;   a.Ko = Kb;   a.Vo = VTb;
  qkv_gemm<<<dim3(32, 8, 3), blk, 0, stream>>>(a);

  attn_fwd<<<dim3(16, 32), blk, 0, stream>>>(Qb, Kb, VTb, ctx);

  out_gemm<<<dim3(64, 8), blk, 0, stream>>>(ctx, Wob, bo, (float*)d_out);
}